// Round 2
// baseline (154.751 us; speedup 1.0000x reference)
//
#include <hip/hip_runtime.h>

#define IMG   224
#define IMG2  (IMG * IMG)          // 50176
#define HO    112
#define WO_   112
#define EMBED 192
#define BATCH 32
#define PPB   (HO * WO_)           // 12544 positions per batch image
#define NPOS  (BATCH * PPB)        // 401408

typedef __attribute__((ext_vector_type(8))) short short8;
typedef __attribute__((ext_vector_type(4))) float float4v;
typedef __attribute__((ext_vector_type(2))) float float2v;

__device__ __forceinline__ short f2bf(float f) {      // fp32 -> bf16 (RNE)
    unsigned u = __builtin_bit_cast(unsigned, f);
    u += 0x7FFFu + ((u >> 16) & 1u);
    return (short)(u >> 16);
}

// Sigmoid-GELU: x*sigmoid(1.702x). Offset error ~4e-4 px, invisible next to
// bf16-conv quantization (absmax 0.031 vs threshold 0.076).
__device__ __forceinline__ float fast_gelu(float a) {
    float e = __builtin_amdgcn_exp2f(a * -2.45546507f);  // exp(-1.702a)
    return a * __builtin_amdgcn_rcpf(1.0f + e);
}

// ---- shared: conv(MFMA) + GELU + projection for one 16-position tile ----
// On return, EVERY lane holds the fully reduced ox[4]/oy[4] for the 4
// positions of its quad (position = tile_base + quad*4 + r).
__device__ __forceinline__ void tile_offsets(
    const float* __restrict__ xb,
    const short8* __restrict__ bfrag,
    const float* __restrict__ owx, const float* __restrict__ owy,
    const int* __restrict__ offj, const bool* __restrict__ isr,
    const bool* __restrict__ k27,
    int ho, int wo0, int col, int quad,
    float ox[4], float oy[4])
{
    int iy0 = 2 * ho - 1;
    int ixl = 2 * (wo0 + col) - 1;
    int base = iy0 * IMG + ixl;

    // A-frag gather. Upper bounds provably in-range (iy,ix <= 223); invalid
    // only when ho==0 (dy==0 row) or wo==0 (dx==0 col) -> wave-uniform branch.
    short8 a;
    if (ho > 0 && wo0 > 0) {
#pragma unroll
        for (int j = 0; j < 8; ++j) {
            float v = isr[j] ? xb[base + offj[j]] : 0.0f;   // offj=0 when !isr
            if (k27[j]) v = 1.0f;
            a[j] = f2bf(v);
        }
    } else {
#pragma unroll
        for (int j = 0; j < 8; ++j) {
            int k  = quad * 8 + j;
            int r9 = k % 9;
            int dy = r9 / 3, dx = r9 % 3;
            bool ok = isr[j] && (iy0 + dy >= 0) && (ixl + dx >= 0);
            int ad = ok ? (base + offj[j]) : 0;
            float v = ok ? xb[ad] : 0.0f;
            if (k27[j]) v = 1.0f;
            a[j] = f2bf(v);
        }
    }

    ox[0] = ox[1] = ox[2] = ox[3] = 0.0f;
    oy[0] = oy[1] = oy[2] = oy[3] = 0.0f;
#pragma unroll
    for (int nt = 0; nt < 12; ++nt) {
        float4v c = {0.0f, 0.0f, 0.0f, 0.0f};
        c = __builtin_amdgcn_mfma_f32_16x16x32_bf16(a, bfrag[nt], c, 0, 0, 0);
#pragma unroll
        for (int r = 0; r < 4; ++r) {
            float g = fast_gelu(c[r]);
            ox[r] = fmaf(g, owx[nt], ox[r]);
            oy[r] = fmaf(g, owy[nt], oy[r]);
        }
    }
    // 16-lane (channel) reduction; stays inside the quad for d<16.
#pragma unroll
    for (int d = 1; d < 16; d <<= 1) {
#pragma unroll
        for (int r = 0; r < 4; ++r) {
            ox[r] += __shfl_xor(ox[r], d, 64);
            oy[r] += __shfl_xor(oy[r], d, 64);
        }
    }
}

// ---- shared: bilinear resample of one (patch, px) column (4 py x 3 ch) ----
__device__ __forceinline__ void resample_patch(
    const float* __restrict__ xb, float* __restrict__ ob,
    int ho, int wo, int px, float ofx, float ofy)
{
    float xs  = 2.0f * wo + 0.25f + 0.5f * px + ofx;
    float x0f = floorf(xs);
    float wx  = xs - x0f;                       // unclamped-floor weight (ref semantics)
    int x0 = (int)x0f; x0 = min(max(x0, 0), IMG - 1);
    int xq = min(x0, IMG - 2);                  // pair base; x1 == xq+1 always
    bool selx = (x0 > xq);                      // x0 == 223 -> v00 = pair.y
    int ocol = wo * 4 + px;

#pragma unroll
    for (int py = 0; py < 4; ++py) {
        float ys  = 2.0f * ho + 0.25f + 0.5f * py + ofy;
        float y0f = floorf(ys);
        float wy  = ys - y0f;
        int y0 = (int)y0f; y0 = min(max(y0, 0), IMG - 1);
        int dyo = (y0 < IMG - 1) ? IMG : 0;     // y1 row offset: {224, 0(clamp)}
        int rb = y0 * IMG + xq;
        int orow = (ho * 4 + py) * 448 + ocol;

#pragma unroll
        for (int c = 0; c < 3; ++c) {
            int v0 = rb + c * IMG2;
            int v1 = v0 + dyo;
            float A0 = xb[v0], A1 = xb[v0 + 1];
            float B0 = xb[v1], B1 = xb[v1 + 1];
            float v00 = selx ? A1 : A0;
            float v10 = selx ? B1 : B0;
            float top = fmaf(wx, A1 - v00, v00);
            float bot = fmaf(wx, B1 - v10, v10);
            ob[c * 200704 + orow] = fmaf(wy, bot - top, top);
        }
    }
}

// ================= Kernel 1: offsets only (MFMA+GELU+proj) =================
// 2 independent waves/block, 64 positions/wave. Writes float2 offsets to ws.
__global__ __launch_bounds__(128)
void offsets_kernel(const float* __restrict__ x,
                    const float* __restrict__ conv_w,
                    const float* __restrict__ conv_b,
                    const float* __restrict__ off_w,
                    float2v* __restrict__ offs) {
    const int lane = threadIdx.x & 63;
    const int wv   = threadIdx.x >> 6;
    const int col  = lane & 15;
    const int quad = lane >> 4;

    const int b   = blockIdx.x / (PPB / 128);                 // uniform: /98
    const int pb0 = (blockIdx.x % (PPB / 128)) * 128 + wv * 64;
    const float* __restrict__ xb = x + (size_t)b * 3 * IMG2;

    int  offj[8];
    bool isr[8], k27[8];
#pragma unroll
    for (int j = 0; j < 8; ++j) {
        int k = quad * 8 + j;
        int c = k / 9, r9 = k % 9;
        int dy = r9 / 3, dx = r9 % 3;
        isr[j] = (k < 27);
        k27[j] = (k == 27);
        offj[j] = isr[j] ? (c * IMG2 + dy * IMG + dx) : 0;
    }

    short8 bfrag[12];
#pragma unroll
    for (int nt = 0; nt < 12; ++nt) {
        int ch = nt * 16 + col;
#pragma unroll
        for (int j = 0; j < 8; ++j) {
            int k = quad * 8 + j;
            float v = (k < 27) ? conv_w[ch * 27 + k]
                               : ((k == 27) ? conv_b[ch] : 0.0f);
            bfrag[nt][j] = f2bf(v);
        }
    }
    float owx[12], owy[12];
#pragma unroll
    for (int nt = 0; nt < 12; ++nt) {
        owx[nt] = off_w[nt * 16 + col] * 2.0f;            // * PATCH_SIZE
        owy[nt] = off_w[EMBED + nt * 16 + col] * 2.0f;
    }

    for (int it = 0; it < 4; ++it) {
        int p   = pb0 + it * 16;
        int ho  = p / WO_;                 // wave-uniform (16 | 112)
        int wo0 = p % WO_;

        float ox[4], oy[4];
        tile_offsets(xb, bfrag, owx, owy, offj, isr, k27,
                     ho, wo0, col, quad, ox, oy);

        // static 3-cndmask select by col&3 (no runtime array index -> no scratch)
        int rsel = col & 3;
        float sx01 = (rsel & 1) ? ox[1] : ox[0];
        float sx23 = (rsel & 1) ? ox[3] : ox[2];
        float vx   = (rsel & 2) ? sx23 : sx01;
        float sy01 = (rsel & 1) ? oy[1] : oy[0];
        float sy23 = (rsel & 1) ? oy[3] : oy[2];
        float vy   = (rsel & 2) ? sy23 : sy01;
        if (col < 4) {
            int gpos = blockIdx.x * 128 + wv * 64 + it * 16 + quad * 4 + rsel;
            float2v o; o[0] = vx; o[1] = vy;
            offs[gpos] = o;                // 16 lanes, 128B contiguous
        }
    }
}

// ================= Kernel 2: resample only (gather + store) ================
// VGPR-lean: __launch_bounds__(256,8) targets <=64 VGPR -> 8 waves/SIMD.
// 4 waves/block, 16 patches/wave, lane = (patch, px).
__global__ __launch_bounds__(256, 8)
void resample_kernel(const float* __restrict__ x,
                     const float2v* __restrict__ offs,
                     float* __restrict__ out) {
    const int lane  = threadIdx.x & 63;
    const int wv    = threadIdx.x >> 6;
    const int patch = lane >> 2;
    const int px    = lane & 3;

    const int b  = blockIdx.x / (PPB / 64);                   // uniform: /196
    const int sb = (blockIdx.x % (PPB / 64)) * 64 + wv * 16;  // wave patch base
    const int ho  = sb / WO_;                                 // wave-uniform
    const int wo0 = sb % WO_;

    const float* __restrict__ xb = x + (size_t)b * 3 * IMG2;
    float* __restrict__ ob = out + (size_t)b * 3 * (448 * 448);

    float2v o = offs[blockIdx.x * 64 + wv * 16 + patch];
    resample_patch(xb, ob, ho, wo0 + patch, px, o[0], o[1]);
}

// ================= Fallback: round-1 fused single kernel ===================
__global__ __launch_bounds__(128)
void fused_kernel(const float* __restrict__ x,
                  const float* __restrict__ conv_w,
                  const float* __restrict__ conv_b,
                  const float* __restrict__ off_w,
                  float* __restrict__ out) {
    const int lane = threadIdx.x & 63;
    const int wv   = threadIdx.x >> 6;
    const int col  = lane & 15;
    const int quad = lane >> 4;

    const int b   = blockIdx.x / (PPB / 128);
    const int pb0 = (blockIdx.x % (PPB / 128)) * 128 + wv * 64;
    const float* __restrict__ xb = x + (size_t)b * 3 * IMG2;
    float* __restrict__ ob = out + (size_t)b * 3 * (448 * 448);

    int  offj[8];
    bool isr[8], k27[8];
#pragma unroll
    for (int j = 0; j < 8; ++j) {
        int k = quad * 8 + j;
        int c = k / 9, r9 = k % 9;
        int dy = r9 / 3, dx = r9 % 3;
        isr[j] = (k < 27);
        k27[j] = (k == 27);
        offj[j] = isr[j] ? (c * IMG2 + dy * IMG + dx) : 0;
    }
    short8 bfrag[12];
#pragma unroll
    for (int nt = 0; nt < 12; ++nt) {
        int ch = nt * 16 + col;
#pragma unroll
        for (int j = 0; j < 8; ++j) {
            int k = quad * 8 + j;
            float v = (k < 27) ? conv_w[ch * 27 + k]
                               : ((k == 27) ? conv_b[ch] : 0.0f);
            bfrag[nt][j] = f2bf(v);
        }
    }
    float owx[12], owy[12];
#pragma unroll
    for (int nt = 0; nt < 12; ++nt) {
        owx[nt] = off_w[nt * 16 + col] * 2.0f;
        owy[nt] = off_w[EMBED + nt * 16 + col] * 2.0f;
    }

    for (int it = 0; it < 4; ++it) {
        int p   = pb0 + it * 16;
        int ho  = p / WO_;
        int wo0 = p % WO_;

        float ox[4], oy[4];
        tile_offsets(xb, bfrag, owx, owy, offj, isr, k27,
                     ho, wo0, col, quad, ox, oy);

        int patch = lane >> 2;
        int rsel  = patch & 3;
        int px    = lane & 3;
        float sx01 = (rsel & 1) ? ox[1] : ox[0];
        float sx23 = (rsel & 1) ? ox[3] : ox[2];
        float ofx  = (rsel & 2) ? sx23 : sx01;
        float sy01 = (rsel & 1) ? oy[1] : oy[0];
        float sy23 = (rsel & 1) ? oy[3] : oy[2];
        float ofy  = (rsel & 2) ? sy23 : sy01;

        resample_patch(xb, ob, ho, wo0 + patch, px, ofx, ofy);
    }
}

extern "C" void kernel_launch(void* const* d_in, const int* in_sizes, int n_in,
                              void* d_out, int out_size, void* d_ws, size_t ws_size,
                              hipStream_t stream) {
    const float* x      = (const float*)d_in[0];
    const float* conv_w = (const float*)d_in[1];
    const float* conv_b = (const float*)d_in[2];
    const float* off_w  = (const float*)d_in[3];
    float* out = (float*)d_out;

    const size_t need = (size_t)NPOS * sizeof(float2v);   // 3.2 MB of offsets
    if (d_ws != nullptr && ws_size >= need) {
        float2v* offs = (float2v*)d_ws;
        offsets_kernel<<<NPOS / 128, 128, 0, stream>>>(x, conv_w, conv_b, off_w, offs);
        resample_kernel<<<NPOS / 64, 256, 0, stream>>>(x, offs, out);
    } else {
        fused_kernel<<<NPOS / 128, 128, 0, stream>>>(x, conv_w, conv_b, off_w, out);
    }
}